// Round 16
// baseline (36641.229 us; speedup 1.0000x reference)
//
#include <hip/hip_runtime.h>
#include <math.h>
#include <stddef.h>

#define NTWO 640
#define DXN 256
#define DNLN 128
#define DINN 64
#define DOUTN 64
#define BATCHN 512
#define HORN 512
#define EPSV 1.0e-3

typedef unsigned int uint;
typedef unsigned short ushort;
typedef _Float16 half2_t __attribute__((ext_vector_type(2)));

__device__ __forceinline__ float fdot2(uint a, uint b, float c) {
#if __has_builtin(__builtin_amdgcn_fdot2)
  return __builtin_amdgcn_fdot2(__builtin_bit_cast(half2_t, a),
                                __builtin_bit_cast(half2_t, b), c, false);
#else
  half2_t x = __builtin_bit_cast(half2_t, a), y = __builtin_bit_cast(half2_t, b);
  return c + (float)x[0] * (float)y[0] + (float)x[1] * (float)y[1];
#endif
}

__device__ __forceinline__ uint pack_f16(float x, float y) {
  _Float16 hx = (_Float16)x, hy = (_Float16)y;
  ushort ux = __builtin_bit_cast(ushort, hx), uy = __builtin_bit_cast(ushort, hy);
  return ((uint)uy << 16) | (uint)ux;
}

__device__ __forceinline__ float fast_exp2(float x) {
#if __has_builtin(__builtin_amdgcn_exp2f)
  return __builtin_amdgcn_exp2f(x);
#else
  return exp2f(x);
#endif
}

__device__ __forceinline__ float bcast_lane(float v, int l) {
#if __has_builtin(__builtin_amdgcn_readlane)
  return __builtin_bit_cast(float, __builtin_amdgcn_readlane(__builtin_bit_cast(int, v), l));
#else
  return __shfl(v, l, 64);
#endif
}

__device__ __forceinline__ uint comp4(const uint4& v, int k) {
  switch (k & 3) {
    case 0: return v.x;
    case 1: return v.y;
    case 2: return v.z;
    default: return v.w;
  }
}

// ---------------- precompute kernels (one-time, f64) ----------------

__global__ void k_xtx(const float* __restrict__ X, double* __restrict__ H) {
  __shared__ float sA[16][17];
  __shared__ float sB[16][17];
  const int tx = threadIdx.x, ty = threadIdx.y;
  const int bi = blockIdx.y * 16, bj = blockIdx.x * 16;
  double acc = 0.0;
  for (int k0 = 0; k0 < NTWO; k0 += 16) {
    sA[ty][tx] = X[(k0 + ty) * NTWO + bi + tx];
    sB[ty][tx] = X[(k0 + ty) * NTWO + bj + tx];
    __syncthreads();
#pragma unroll
    for (int kk = 0; kk < 16; ++kk)
      acc += (double)sA[kk][ty] * (double)sB[kk][tx];
    __syncthreads();
  }
  const int i = bi + ty, j = bj + tx;
  if (i == j) acc += EPSV;
  H[i * NTWO + j] = acc;
}

// fused prep: E, sc, B2/C2 casts, Dxt, Eye2, and Mxd = sc*(-H21) (128x256 f64)
__global__ void k_prep(const double* __restrict__ H, const float* __restrict__ Y,
                       const float* __restrict__ B2, const float* __restrict__ C2,
                       const float* __restrict__ D21,
                       double* __restrict__ E, double* __restrict__ scv,
                       double* __restrict__ B2d, double* __restrict__ C2d,
                       double* __restrict__ Dxt, double* __restrict__ Eye2,
                       double* __restrict__ Mxd) {
  int idx = blockIdx.x * 256 + threadIdx.x;
  if (idx < 65536) {
    int i = idx >> 8, j = idx & 255;
    E[idx] = 0.5 * (H[i * NTWO + j] + H[(384 + i) * NTWO + 384 + j]
                    + (double)Y[i * 256 + j] - (double)Y[j * 256 + i]);
    return;
  }
  idx -= 65536;
  if (idx < 128) {
    double lam = 0.5 * H[(256 + idx) * NTWO + 256 + idx];
    scv[idx] = 2.8853900817779268 / lam;
    return;
  }
  idx -= 128;
  if (idx < 16384) { B2d[idx] = (double)B2[idx]; return; }
  idx -= 16384;
  if (idx < 16384) { C2d[idx] = (double)C2[idx]; return; }
  idx -= 16384;
  if (idx < 28672) {
    int r = idx / 448, c = idx % 448;
    double v = 0.0;
    if (c >= 256 && c < 384) v = (double)D21[r * 128 + (c - 256)];
    Dxt[idx] = v;
    return;
  }
  idx -= 28672;
  if (idx < 16384) {
    int r = idx >> 7, c = idx & 127;
    Eye2[idx] = (r == c) ? 2.0 : 0.0;
    return;
  }
  idx -= 16384;
  if (idx < 32768) {  // Mxd[r][c] = -H21[r][c] * sc_r  (inline sc, no dependency)
    int r = idx >> 8, c = idx & 255;
    double sc_r = 2.8853900817779268 / (0.5 * H[(256 + r) * NTWO + 256 + r]);
    Mxd[idx] = -H[(256 + r) * NTWO + c] * sc_r;
  }
}

__global__ void k_ginv32(const double* __restrict__ A, int lda, float* __restrict__ Out) {
  __shared__ float M[128 * 129];
  const int tid = threadIdx.x;
  for (int i = tid; i < 128 * 128; i += 256)
    M[(i >> 7) * 129 + (i & 127)] = (float)A[(i >> 7) * lda + (i & 127)];
  __syncthreads();
  for (int k = 0; k < 128; ++k) {
    float ip = 1.0f / M[k * 129 + k];
    __syncthreads();
    if (tid < 128) {
      float v = M[k * 129 + tid];
      M[k * 129 + tid] = (tid == k) ? ip : v * ip;
    }
    __syncthreads();
    const int i0 = tid >> 1, half = tid & 1;
    float f = (i0 != k) ? M[i0 * 129 + k] : 0.0f;
    __syncthreads();
    if (i0 != k) {
      const float* rk = M + k * 129;
      float* ri = M + i0 * 129;
      const int j0 = half * 64;
#pragma unroll 8
      for (int j = j0; j < j0 + 64; ++j) {
        float v = (j == k) ? 0.0f : ri[j];
        ri[j] = v - f * rk[j];
      }
    }
    __syncthreads();
  }
  for (int i = tid; i < 128 * 128; i += 256) Out[i] = M[(i >> 7) * 129 + (i & 127)];
}

__global__ void k_dgemm(int M, int N, int K,
                        const double* __restrict__ A, int lda,
                        const double* __restrict__ B, int ldb,
                        double alpha,
                        const double* __restrict__ D, int ldd, double beta,
                        double* __restrict__ C, int ldc) {
  __shared__ double sA[16][17];
  __shared__ double sB[16][17];
  const int tx = threadIdx.x, ty = threadIdx.y;
  const int row = blockIdx.y * 16 + ty, col = blockIdx.x * 16 + tx;
  double acc = 0.0;
  for (int k0 = 0; k0 < K; k0 += 16) {
    sA[ty][tx] = A[row * lda + k0 + tx];
    sB[ty][tx] = B[(k0 + ty) * ldb + col];
    __syncthreads();
#pragma unroll
    for (int kk = 0; kk < 16; ++kk) acc += sA[ty][kk] * sB[kk][tx];
    __syncthreads();
  }
  double v = alpha * acc;
  if (beta != 0.0) v += beta * D[row * ldd + col];
  C[row * ldc + col] = v;
}

__global__ void k_copyblk(const double* __restrict__ S, int lds,
                          double* __restrict__ Dst, int ldd, int total, int cols) {
  int idx = blockIdx.x * 256 + threadIdx.x;
  if (idx < total) {
    int r = idx / cols, c = idx % cols;
    Dst[r * ldd + c] = S[r * lds + c];
  }
}

__global__ void k_cast_f2d(const float* __restrict__ s, double* __restrict__ d, int n) {
  int i = blockIdx.x * 256 + threadIdx.x;
  if (i < n) d[i] = (double)s[i];
}

// fused pack: Msh, OmWh, Tp1g, Tp2g (R9 layouts) + fold matrices:
// MxAxg (128r x 128dw k-major), MxAwg (128r x 64dw), Mug (128r x 32dw, sc*D12),
// MxAug (128r x 32dw). k-major dword layout: [((d>>2)*128 + r)*4 + (d&3)].
__global__ void k_pack(const double* __restrict__ H, const float* __restrict__ D12,
                       const double* __restrict__ sc, const double* __restrict__ Axwu,
                       const double* __restrict__ G,
                       const double* __restrict__ MxAxd, const double* __restrict__ MxAwd,
                       const double* __restrict__ MxAud,
                       uint* __restrict__ Msh, uint* __restrict__ OmWh,
                       uint* __restrict__ Tp1g, uint* __restrict__ Tp2g,
                       uint* __restrict__ MxAxg, uint* __restrict__ MxAwg,
                       uint* __restrict__ Mug, uint* __restrict__ MxAug) {
  int idx = blockIdx.x * 256 + threadIdx.x;
  if (idx < 448 * 160) {
    int rr = idx / 160, d = idx % 160;
    float v[2];
#pragma unroll
    for (int e = 0; e < 2; ++e) {
      int k = 2 * d + e;
      double x;
      if (rr < 128) {
        double s = sc[rr];
        x = (k < 256) ? (-H[(256 + rr) * NTWO + k] * s)
                      : ((double)D12[rr * DINN + (k - 256)] * s);
      } else {
        int r2 = rr - 128;
        const double* src = (r2 < 256) ? (Axwu + (size_t)r2 * 448) : (G + (size_t)(r2 - 256) * 448);
        x = (k < 256) ? src[k] : src[384 + (k - 256)];
      }
      v[e] = (float)x;
    }
    Msh[((size_t)(d >> 2) * 448 + rr) * 4 + (d & 3)] = pack_f16(v[0], v[1]);
    return;
  }
  idx -= 448 * 160;
  if (idx < 320 * 64) {
    int rr = idx / 64, d = idx % 64;
    float v[2];
#pragma unroll
    for (int e = 0; e < 2; ++e) {
      int j = 2 * d + e;
      double x = (rr < 256) ? Axwu[(size_t)rr * 448 + 256 + j]
                            : G[(size_t)(rr - 256) * 448 + 256 + j];
      v[e] = (float)x;
    }
    OmWh[((size_t)(d >> 2) * 320 + rr) * 4 + (d & 3)] = pack_f16(v[0], v[1]);
    return;
  }
  idx -= 320 * 64;
  if (idx < 4096) {
    int l = idx >> 6, d = idx & 63;
    float lo = (l > d) ? (float)(-H[(256 + l) * NTWO + 256 + d] * sc[l]) : 0.0f;
    float hi = (float)(-H[(256 + l + 64) * NTWO + 256 + d] * sc[l + 64]);
    Tp1g[idx] = pack_f16(lo, hi);
    return;
  }
  idx -= 4096;
  if (idx < 2048) {
    int l = idx >> 5, i = idx & 31;
    int j0 = 64 + 2 * i, j1 = j0 + 1;
    float v0 = (l + 64 > j0) ? (float)(-H[(256 + l + 64) * NTWO + 256 + j0] * sc[l + 64]) : 0.0f;
    float v1 = (l + 64 > j1) ? (float)(-H[(256 + l + 64) * NTWO + 256 + j1] * sc[l + 64]) : 0.0f;
    Tp2g[idx] = pack_f16(v0, v1);
    return;
  }
  idx -= 2048;
  if (idx < 16384) {  // MxAxg: r = idx>>7, d = idx&127
    int r = idx >> 7, d = idx & 127;
    MxAxg[((size_t)(d >> 2) * 128 + r) * 4 + (d & 3)] =
        pack_f16((float)MxAxd[r * 256 + 2 * d], (float)MxAxd[r * 256 + 2 * d + 1]);
    return;
  }
  idx -= 16384;
  if (idx < 8192) {  // MxAwg: r = idx>>6, d = idx&63
    int r = idx >> 6, d = idx & 63;
    MxAwg[((size_t)(d >> 2) * 128 + r) * 4 + (d & 3)] =
        pack_f16((float)MxAwd[r * 128 + 2 * d], (float)MxAwd[r * 128 + 2 * d + 1]);
    return;
  }
  idx -= 8192;
  if (idx < 4096) {  // Mug: r = idx>>5, d = idx&31 (sc*D12)
    int r = idx >> 5, d = idx & 31;
    float s = (float)sc[r];
    Mug[((size_t)(d >> 2) * 128 + r) * 4 + (d & 3)] =
        pack_f16(s * D12[r * 64 + 2 * d], s * D12[r * 64 + 2 * d + 1]);
    return;
  }
  idx -= 4096;
  if (idx < 4096) {  // MxAug: r = idx>>5, d = idx&31
    int r = idx >> 5, d = idx & 31;
    MxAug[((size_t)(d >> 2) * 128 + r) * 4 + (d & 3)] =
        pack_f16((float)MxAud[r * 64 + 2 * d], (float)MxAud[r * 64 + 2 * d + 1]);
  }
}

// ---------------- main scan: 256 WGs x 512 threads, NS=2, 1 WG/CU ----------------
// Fold: base_t = baseAcc_t (streams, prev window) + MxAw.w_{t-1} (own) + Mu.u_t.
// Chain waves never wait on x_t: prologue = 2 LDS floats + 24 uint4-dots.
// Streams: R9 Phase A/C + baseAcc_{t+1} = MxAx.x_t + MxAu.u_t (x-threads).
__global__ __launch_bounds__(512)
void k_scan(const float* __restrict__ u_in, const uint* __restrict__ Msh,
            const uint* __restrict__ OmWh, const uint* __restrict__ Tp1g,
            const uint* __restrict__ Tp2g, const uint* __restrict__ MxAxg,
            const uint* __restrict__ MxAwg, const uint* __restrict__ Mug,
            const uint* __restrict__ MxAug, float* __restrict__ out) {
  __shared__ uint4 MxAwL4[16 * 128];              // 32 KB k-major
  __shared__ uint4 MuL4[8 * 128];                 // 16 KB k-major
  __shared__ uint Tp1L[64 * 68];                  // 17 KB
  __shared__ uint Tp2L[64 * 36];                  // 9 KB
  __shared__ float baseAccL[2][256];              // 2 KB (dbl-buffered)
  __shared__ uint __align__(16) zL[2 * 164];      // z = [x(128dw);u(32dw)] x 2
  __shared__ uint __align__(16) wvhL[2 * 64];     // w f16-packed
  const int tid = threadIdx.x;
  const int s0 = blockIdx.x * 2;
  const uint4* __restrict__ mp4 = (const uint4*)Msh;
  const uint4* __restrict__ op4 = (const uint4*)OmWh;

  // one-time init
  for (int i = tid; i < 2048; i += 512) MxAwL4[i] = ((const uint4*)MxAwg)[i];
  for (int i = tid; i < 1024; i += 512) MuL4[i] = ((const uint4*)Mug)[i];
  for (int i = tid; i < 4096; i += 512) Tp1L[(i >> 6) * 68 + (i & 63)] = Tp1g[i];
  for (int i = tid; i < 2048; i += 512) Tp2L[(i >> 5) * 36 + (i & 31)] = Tp2g[i];
  if (tid < 256) { zL[(tid >> 7) * 164 + (tid & 127)] = 0u; baseAccL[0][tid] = 0.0f; }
  if (tid < 128) {
    wvhL[tid] = 0u;  // w_{-1} = 0
    out[((size_t)(s0 + (tid >> 6)) * HORN) * DOUTN + (tid & 63)] = 0.0f;
  }
  if (tid >= 448) {
    const int i = tid - 448, s = i >> 5, k = i & 31;
    const float* up = u_in + ((size_t)(s0 + s) * HORN) * DINN + 2 * k;
    zL[s * 164 + 128 + k] = pack_f16(up[0], up[1]);
  }
  __syncthreads();

  for (int t = 0; t < HORN - 1; ++t) {
    float a0 = 0.f, a1 = 0.f;
    float unx = 0.f, uny = 0.f;
    uint4 om[16];
    if (tid < 128) {
      // ---- chain waves: hot base assembly (no z-dots, no x_t dependency)
      const int b = tid >> 6, l = tid & 63;
      float c0 = baseAccL[t & 1][b * 128 + l];
      float c1 = baseAccL[t & 1][b * 128 + 64 + l];
      {
        const uint4* wp = (const uint4*)(wvhL + b * 64);  // w_{t-1} (own wave's)
#pragma unroll
        for (int i = 0; i < 16; ++i) {
          const uint4 mA = MxAwL4[i * 128 + l];
          const uint4 mB = MxAwL4[i * 128 + 64 + l];
          const uint4 p = wp[i];
          c0 = fdot2(mA.x, p.x, c0); c0 = fdot2(mA.y, p.y, c0);
          c0 = fdot2(mA.z, p.z, c0); c0 = fdot2(mA.w, p.w, c0);
          c1 = fdot2(mB.x, p.x, c1); c1 = fdot2(mB.y, p.y, c1);
          c1 = fdot2(mB.z, p.z, c1); c1 = fdot2(mB.w, p.w, c1);
        }
        const uint4* up = (const uint4*)(zL + b * 164 + 128);  // u_t
#pragma unroll
        for (int i = 0; i < 8; ++i) {
          const uint4 mA = MuL4[i * 128 + l];
          const uint4 mB = MuL4[i * 128 + 64 + l];
          const uint4 p = up[i];
          c0 = fdot2(mA.x, p.x, c0); c0 = fdot2(mA.y, p.y, c0);
          c0 = fdot2(mA.z, p.z, c0); c0 = fdot2(mA.w, p.w, c0);
          c1 = fdot2(mB.x, p.x, c1); c1 = fdot2(mB.y, p.y, c1);
          c1 = fdot2(mB.z, p.z, c1); c1 = fdot2(mB.w, p.w, c1);
        }
      }
      // ---- T bulk-prefetch + R9 chain body
      uint4 q[16], r2[8];
      {
        const uint* tp1 = Tp1L + l * 68;
        const uint* tp2 = Tp2L + l * 36;
#pragma unroll
        for (int i = 0; i < 16; ++i) q[i] = *(const uint4*)(tp1 + 4 * i);
#pragma unroll
        for (int i = 0; i < 8; ++i) r2[i] = *(const uint4*)(tp2 + 4 * i);
      }
      __builtin_amdgcn_s_setprio(1);
      float wx = 0.f, wy = 0.f;
#pragma unroll
      for (int j = 0; j < 64; ++j) {
        const float av = bcast_lane(c0, j);
        const float sx = fast_exp2(av);
        const float rc = __builtin_amdgcn_rcpf(sx + 1.0f);
        const float w = __builtin_fmaf(-2.0f, rc, 1.0f);
        if (l == (j >> 1)) { if (j & 1) wy = w; else wx = w; }
        const half2_t h = __builtin_bit_cast(half2_t, comp4(q[j >> 2], j & 3));
        c0 = __builtin_fmaf((float)h[0], w, c0);
        c1 = __builtin_fmaf((float)h[1], w, c1);
      }
#pragma unroll
      for (int j = 64; j < 128; ++j) {
        const float av = bcast_lane(c1, j - 64);
        const float sx = fast_exp2(av);
        const float rc = __builtin_amdgcn_rcpf(sx + 1.0f);
        const float w = __builtin_fmaf(-2.0f, rc, 1.0f);
        if (l == (j >> 1)) { if (j & 1) wy = w; else wx = w; }
        const int i2 = j - 64;
        const half2_t h = __builtin_bit_cast(half2_t, comp4(r2[i2 >> 3], (i2 >> 1) & 3));
        const float tv = (i2 & 1) ? (float)h[1] : (float)h[0];
        c1 = __builtin_fmaf(tv, w, c1);
      }
      __builtin_amdgcn_s_setprio(0);
      wvhL[b * 64 + l] = pack_f16(wx, wy);
    } else if (tid < 448) {
      // ---- stream threads: Msh row-dots (both samples) + om prefetch
      const int row = tid;
      const uint4* z0 = (const uint4*)zL;
      const uint4* z1 = (const uint4*)(zL + 164);
      uint4 mbuf[20];
#pragma unroll
      for (int i = 0; i < 20; ++i) mbuf[i] = mp4[(size_t)i * 448 + row];
#pragma unroll
      for (int i = 0; i < 20; ++i) {
        const uint4 m = mbuf[i];
        const uint4 p = z0[i], q = z1[i];
        a0 = fdot2(m.x, p.x, a0); a0 = fdot2(m.y, p.y, a0);
        a0 = fdot2(m.z, p.z, a0); a0 = fdot2(m.w, p.w, a0);
        a1 = fdot2(m.x, q.x, a1); a1 = fdot2(m.y, q.y, a1);
        a1 = fdot2(m.z, q.z, a1); a1 = fdot2(m.w, q.w, a1);
      }
#pragma unroll
      for (int i = 0; i < 20; ++i) mbuf[i] = mp4[(size_t)(20 + i) * 448 + row];
#pragma unroll
      for (int i = 0; i < 20; ++i) {
        const uint4 m = mbuf[i];
        const uint4 p = z0[20 + i], q = z1[20 + i];
        a0 = fdot2(m.x, p.x, a0); a0 = fdot2(m.y, p.y, a0);
        a0 = fdot2(m.z, p.z, a0); a0 = fdot2(m.w, p.w, a0);
        a1 = fdot2(m.x, q.x, a1); a1 = fdot2(m.y, q.y, a1);
        a1 = fdot2(m.z, q.z, a1); a1 = fdot2(m.w, q.w, a1);
      }
      const int rr = row - 128;
#pragma unroll
      for (int i = 0; i < 16; ++i) om[i] = op4[(size_t)i * 320 + rr];
      // ---- x-threads additionally: baseAcc_{t+1} = MxAx.x_t + MxAu.u_t
      if (tid < 384) {
        const int br = (tid - 128) >> 1, bs = (tid - 128) & 1;
        const uint4* zx = (const uint4*)(zL + bs * 164);
        const uint4* zu = zx + 32;
        float bacc = 0.f;
        const uint4* xp = (const uint4*)MxAxg;
#pragma unroll 8
        for (int i = 0; i < 32; ++i) {
          const uint4 m = xp[(size_t)i * 128 + br];
          const uint4 p = zx[i];
          bacc = fdot2(m.x, p.x, bacc); bacc = fdot2(m.y, p.y, bacc);
          bacc = fdot2(m.z, p.z, bacc); bacc = fdot2(m.w, p.w, bacc);
        }
        const uint4* aup = (const uint4*)MxAug;
#pragma unroll
        for (int i = 0; i < 8; ++i) {
          const uint4 m = aup[(size_t)i * 128 + br];
          const uint4 p = zu[i];
          bacc = fdot2(m.x, p.x, bacc); bacc = fdot2(m.y, p.y, bacc);
          bacc = fdot2(m.z, p.z, bacc); bacc = fdot2(m.w, p.w, bacc);
        }
        baseAccL[(t + 1) & 1][bs * 128 + br] = bacc;
      }
    } else {
      // ---- wave 7: u prefetch
      const int i = tid - 448, s = i >> 5, k = i & 31;
      const float* up = u_in + ((size_t)(s0 + s) * HORN + (t + 1)) * DINN + 2 * k;
      unx = up[0]; uny = up[1];
    }
    __syncthreads();  // B1: w_t ready; stream dots done; OmW in flight

    if (tid >= 128 && tid < 448) {
      const int row = tid;
      const uint4* wp0 = (const uint4*)wvhL;
      const uint4* wp1 = (const uint4*)(wvhL + 64);
#pragma unroll
      for (int i = 0; i < 16; ++i) {
        const uint4 m = om[i];
        const uint4 p = wp0[i], q = wp1[i];
        a0 = fdot2(m.x, p.x, a0); a0 = fdot2(m.y, p.y, a0);
        a0 = fdot2(m.z, p.z, a0); a0 = fdot2(m.w, p.w, a0);
        a1 = fdot2(m.x, q.x, a1); a1 = fdot2(m.y, q.y, a1);
        a1 = fdot2(m.z, q.z, a1); a1 = fdot2(m.w, q.w, a1);
      }
      if (row < 384) {
        const float n0 = __shfl_down(a0, 1, 64);
        const float n1 = __shfl_down(a1, 1, 64);
        if ((row & 1) == 0) {
          const int d = (row - 128) >> 1;
          zL[d] = pack_f16(a0, n0);
          zL[164 + d] = pack_f16(a1, n1);
        }
      } else {
        const int yr = row - 384;
        out[((size_t)s0 * HORN + (t + 1)) * DOUTN + yr] = a0;
        out[((size_t)(s0 + 1) * HORN + (t + 1)) * DOUTN + yr] = a1;
      }
    } else if (tid >= 448) {
      const int i = tid - 448, s = i >> 5, k = i & 31;
      zL[s * 164 + 128 + k] = pack_f16(unx, uny);
    }
    __syncthreads();  // B2: z_{t+1} + u_{t+1} ready
  }
}

// ---------------- host ----------------
extern "C" void kernel_launch(void* const* d_in, const int* in_sizes, int n_in,
                              void* d_out, int out_size, void* d_ws, size_t ws_size,
                              hipStream_t stream) {
  (void)in_sizes; (void)n_in; (void)out_size; (void)ws_size;
  const float* u_in = (const float*)d_in[0];
  const float* X    = (const float*)d_in[1];
  const float* Y    = (const float*)d_in[2];
  const float* B2   = (const float*)d_in[3];
  const float* C2   = (const float*)d_in[4];
  const float* D21  = (const float*)d_in[5];
  const float* D12  = (const float*)d_in[6];
  float* out = (float*)d_out;

  double* H     = (double*)d_ws;           // 640*640
  double* E     = H + 640 * 640;           // 256*256
  double* Ai    = E + 256 * 256;           // 128*128
  double* CMm   = Ai + 128 * 128;
  double* MBm   = CMm + 128 * 128;
  double* Sm    = MBm + 128 * 128;
  double* Tm    = Sm + 128 * 128;
  double* Einv  = Tm + 128 * 128;          // 256*256
  double* Axwu  = Einv + 256 * 256;        // 256*448
  double* G     = Axwu + 256 * 448;        // 64*448
  double* B2d   = G + 64 * 448;            // 256*64
  double* C2d   = B2d + 256 * 64;          // 64*256
  double* Dxt   = C2d + 64 * 256;          // 64*448
  double* Eye2  = Dxt + 64 * 448;          // 128*128
  double* M0d   = Eye2 + 128 * 128;
  double* Rb    = M0d + 128 * 128;
  double* Mxd   = Rb + 128 * 128;          // 128*256
  double* MxAxd = Mxd + 128 * 256;         // 128*256
  double* MxAwd = MxAxd + 128 * 256;       // 128*128
  double* MxAud = MxAwd + 128 * 128;       // 128*64
  double* scv   = MxAud + 128 * 64;        // 128
  float*  F32   = (float*)(scv + 128);     // 128*128
  uint*   Msh   = (uint*)(F32 + 128 * 128);// 71680
  uint*   OmWh  = Msh + 71680;             // 20480
  uint*   Tp1g  = OmWh + 20480;            // 4096
  uint*   Tp2g  = Tp1g + 4096;             // 2048
  uint*   MxAxg = Tp2g + 2048;             // 16384
  uint*   MxAwg = MxAxg + 16384;           // 8192
  uint*   Mug   = MxAwg + 8192;            // 4096
  uint*   MxAug = Mug + 4096;              // 4096

  dim3 blk16(16, 16);
  k_xtx<<<dim3(40, 40), blk16, 0, stream>>>(X, H);
  k_prep<<<689, 256, 0, stream>>>(H, Y, B2, C2, D21, E, scv, B2d, C2d, Dxt, Eye2, Mxd);

  auto inv128 = [&](const double* A, int lda, double* Out) {
    k_ginv32<<<1, 256, 0, stream>>>(A, lda, F32);
    k_cast_f2d<<<64, 256, 0, stream>>>(F32, M0d, 128 * 128);
    // one Newton-Schulz refinement: M <- M0(2I - A M0)
    k_dgemm<<<dim3(8, 8), blk16, 0, stream>>>(128, 128, 128, A, lda, M0d, 128, -1.0, Eye2, 128, 1.0, Rb, 128);
    k_dgemm<<<dim3(8, 8), blk16, 0, stream>>>(128, 128, 128, M0d, 128, Rb, 128, 1.0, (const double*)nullptr, 0, 0.0, Out, 128);
  };

  const double* EA = E;
  const double* EB = E + 128;
  const double* EC = E + 128 * 256;
  const double* ED = E + 128 * 256 + 128;

  inv128(EA, 256, Ai);
  k_dgemm<<<dim3(8, 8), blk16, 0, stream>>>(128, 128, 128, EC, 256, Ai, 128, 1.0, (const double*)nullptr, 0, 0.0, CMm, 128);
  k_dgemm<<<dim3(8, 8), blk16, 0, stream>>>(128, 128, 128, Ai, 128, EB, 256, 1.0, (const double*)nullptr, 0, 0.0, MBm, 128);
  k_dgemm<<<dim3(8, 8), blk16, 0, stream>>>(128, 128, 128, CMm, 128, EB, 256, -1.0, ED, 256, 1.0, Sm, 128);
  inv128(Sm, 128, Tm);
  k_dgemm<<<dim3(8, 8), blk16, 0, stream>>>(128, 128, 128, Tm, 128, CMm, 128, -1.0, (const double*)nullptr, 0, 0.0, Einv + 128 * 256, 256);
  k_dgemm<<<dim3(8, 8), blk16, 0, stream>>>(128, 128, 128, MBm, 128, Tm, 128, -1.0, (const double*)nullptr, 0, 0.0, Einv + 128, 256);
  k_dgemm<<<dim3(8, 8), blk16, 0, stream>>>(128, 128, 128, MBm, 128, Einv + 128 * 256, 256, -1.0, Ai, 128, 1.0, Einv, 256);
  k_copyblk<<<64, 256, 0, stream>>>(Tm, 128, Einv + 128 * 256 + 128, 256, 128 * 128, 128);

  // Axwu = Einv @ [Fm | B1 | B2]
  k_dgemm<<<dim3(24, 16), blk16, 0, stream>>>(256, 384, 256, Einv, 256, H + 384 * NTWO, NTWO, 1.0, (const double*)nullptr, 0, 0.0, Axwu, 448);
  k_dgemm<<<dim3(4, 16), blk16, 0, stream>>>(256, 64, 256, Einv, 256, B2d, 64, 1.0, (const double*)nullptr, 0, 0.0, Axwu + 384, 448);
  // G = C2 @ Axwu + [0 | D21 | 0]
  k_dgemm<<<dim3(28, 4), blk16, 0, stream>>>(64, 448, 256, C2d, 256, Axwu, 448, 1.0, Dxt, 448, 1.0, G, 448);
  // fold matrices: MxAx (128x256), MxAw (128x128), MxAu (128x64)
  k_dgemm<<<dim3(16, 8), blk16, 0, stream>>>(128, 256, 256, Mxd, 256, Axwu, 448, 1.0, (const double*)nullptr, 0, 0.0, MxAxd, 256);
  k_dgemm<<<dim3(8, 8), blk16, 0, stream>>>(128, 128, 256, Mxd, 256, Axwu + 256, 448, 1.0, (const double*)nullptr, 0, 0.0, MxAwd, 128);
  k_dgemm<<<dim3(4, 8), blk16, 0, stream>>>(128, 64, 256, Mxd, 256, Axwu + 384, 448, 1.0, (const double*)nullptr, 0, 0.0, MxAud, 64);

  k_pack<<<512, 256, 0, stream>>>(H, D12, scv, Axwu, G, MxAxd, MxAwd, MxAud,
                                  Msh, OmWh, Tp1g, Tp2g, MxAxg, MxAwg, Mug, MxAug);

  k_scan<<<BATCHN / 2, 512, 0, stream>>>(u_in, Msh, OmWh, Tp1g, Tp2g,
                                         MxAxg, MxAwg, Mug, MxAug, out);
}

// Round 17
// 4243.903 us; speedup vs baseline: 8.6339x; 8.6339x over previous
//
#include <hip/hip_runtime.h>
#include <math.h>
#include <stddef.h>

#define NTWO 640
#define DXN 256
#define DNLN 128
#define DINN 64
#define DOUTN 64
#define BATCHN 512
#define HORN 512
#define EPSV 1.0e-3

typedef unsigned int uint;
typedef unsigned short ushort;
typedef _Float16 half2_t __attribute__((ext_vector_type(2)));

__device__ __forceinline__ float fdot2(uint a, uint b, float c) {
#if __has_builtin(__builtin_amdgcn_fdot2)
  return __builtin_amdgcn_fdot2(__builtin_bit_cast(half2_t, a),
                                __builtin_bit_cast(half2_t, b), c, false);
#else
  half2_t x = __builtin_bit_cast(half2_t, a), y = __builtin_bit_cast(half2_t, b);
  return c + (float)x[0] * (float)y[0] + (float)x[1] * (float)y[1];
#endif
}

__device__ __forceinline__ uint pack_f16(float x, float y) {
  _Float16 hx = (_Float16)x, hy = (_Float16)y;
  ushort ux = __builtin_bit_cast(ushort, hx), uy = __builtin_bit_cast(ushort, hy);
  return ((uint)uy << 16) | (uint)ux;
}

__device__ __forceinline__ float fast_exp2(float x) {
#if __has_builtin(__builtin_amdgcn_exp2f)
  return __builtin_amdgcn_exp2f(x);
#else
  return exp2f(x);
#endif
}

__device__ __forceinline__ float bcast_lane(float v, int l) {
#if __has_builtin(__builtin_amdgcn_readlane)
  return __builtin_bit_cast(float, __builtin_amdgcn_readlane(__builtin_bit_cast(int, v), l));
#else
  return __shfl(v, l, 64);
#endif
}

__device__ __forceinline__ uint comp4(const uint4& v, int k) {
  switch (k & 3) {
    case 0: return v.x;
    case 1: return v.y;
    case 2: return v.z;
    default: return v.w;
  }
}

// ---------------- precompute kernels (one-time, f64) ----------------

__global__ void k_xtx(const float* __restrict__ X, double* __restrict__ H) {
  __shared__ float sA[16][17];
  __shared__ float sB[16][17];
  const int tx = threadIdx.x, ty = threadIdx.y;
  const int bi = blockIdx.y * 16, bj = blockIdx.x * 16;
  double acc = 0.0;
  for (int k0 = 0; k0 < NTWO; k0 += 16) {
    sA[ty][tx] = X[(k0 + ty) * NTWO + bi + tx];
    sB[ty][tx] = X[(k0 + ty) * NTWO + bj + tx];
    __syncthreads();
#pragma unroll
    for (int kk = 0; kk < 16; ++kk)
      acc += (double)sA[kk][ty] * (double)sB[kk][tx];
    __syncthreads();
  }
  const int i = bi + ty, j = bj + tx;
  if (i == j) acc += EPSV;
  H[i * NTWO + j] = acc;
}

// fused small prep: E, sc, B2 cast, C2 cast, Dxt, Eye2
__global__ void k_prep(const double* __restrict__ H, const float* __restrict__ Y,
                       const float* __restrict__ B2, const float* __restrict__ C2,
                       const float* __restrict__ D21,
                       double* __restrict__ E, double* __restrict__ scv,
                       double* __restrict__ B2d, double* __restrict__ C2d,
                       double* __restrict__ Dxt, double* __restrict__ Eye2) {
  int idx = blockIdx.x * 256 + threadIdx.x;
  if (idx < 65536) {
    int i = idx >> 8, j = idx & 255;
    E[idx] = 0.5 * (H[i * NTWO + j] + H[(384 + i) * NTWO + 384 + j]
                    + (double)Y[i * 256 + j] - (double)Y[j * 256 + i]);
    return;
  }
  idx -= 65536;
  if (idx < 128) {
    double lam = 0.5 * H[(256 + idx) * NTWO + 256 + idx];
    scv[idx] = 2.8853900817779268 / lam;
    return;
  }
  idx -= 128;
  if (idx < 16384) { B2d[idx] = (double)B2[idx]; return; }
  idx -= 16384;
  if (idx < 16384) { C2d[idx] = (double)C2[idx]; return; }
  idx -= 16384;
  if (idx < 28672) {
    int r = idx / 448, c = idx % 448;
    double v = 0.0;
    if (c >= 256 && c < 384) v = (double)D21[r * 128 + (c - 256)];
    Dxt[idx] = v;
    return;
  }
  idx -= 28672;
  if (idx < 16384) {
    int r = idx >> 7, c = idx & 127;
    Eye2[idx] = (r == c) ? 2.0 : 0.0;
  }
}

// fp32 Gauss-Jordan inverse of 128x128 (no pivot; symmetric-part-PD input).
__global__ void k_ginv32(const double* __restrict__ A, int lda, float* __restrict__ Out) {
  __shared__ float M[128 * 129];
  const int tid = threadIdx.x;
  for (int i = tid; i < 128 * 128; i += 256)
    M[(i >> 7) * 129 + (i & 127)] = (float)A[(i >> 7) * lda + (i & 127)];
  __syncthreads();
  for (int k = 0; k < 128; ++k) {
    float ip = 1.0f / M[k * 129 + k];
    __syncthreads();
    if (tid < 128) {
      float v = M[k * 129 + tid];
      M[k * 129 + tid] = (tid == k) ? ip : v * ip;
    }
    __syncthreads();
    const int i0 = tid >> 1, half = tid & 1;
    float f = (i0 != k) ? M[i0 * 129 + k] : 0.0f;
    __syncthreads();
    if (i0 != k) {
      const float* rk = M + k * 129;
      float* ri = M + i0 * 129;
      const int j0 = half * 64;
#pragma unroll 8
      for (int j = j0; j < j0 + 64; ++j) {
        float v = (j == k) ? 0.0f : ri[j];
        ri[j] = v - f * rk[j];
      }
    }
    __syncthreads();
  }
  for (int i = tid; i < 128 * 128; i += 256) Out[i] = M[(i >> 7) * 129 + (i & 127)];
}

__global__ void k_dgemm(int M, int N, int K,
                        const double* __restrict__ A, int lda,
                        const double* __restrict__ B, int ldb,
                        double alpha,
                        const double* __restrict__ D, int ldd, double beta,
                        double* __restrict__ C, int ldc) {
  __shared__ double sA[16][17];
  __shared__ double sB[16][17];
  const int tx = threadIdx.x, ty = threadIdx.y;
  const int row = blockIdx.y * 16 + ty, col = blockIdx.x * 16 + tx;
  double acc = 0.0;
  for (int k0 = 0; k0 < K; k0 += 16) {
    sA[ty][tx] = A[row * lda + k0 + tx];
    sB[ty][tx] = B[(k0 + ty) * ldb + col];
    __syncthreads();
#pragma unroll
    for (int kk = 0; kk < 16; ++kk) acc += sA[ty][kk] * sB[kk][tx];
    __syncthreads();
  }
  double v = alpha * acc;
  if (beta != 0.0) v += beta * D[row * ldd + col];
  C[row * ldc + col] = v;
}

__global__ void k_copyblk(const double* __restrict__ S, int lds,
                          double* __restrict__ Dst, int ldd, int total, int cols) {
  int idx = blockIdx.x * 256 + threadIdx.x;
  if (idx < total) {
    int r = idx / cols, c = idx % cols;
    Dst[r * ldd + c] = S[r * lds + c];
  }
}

__global__ void k_cast_f2d(const float* __restrict__ s, double* __restrict__ d, int n) {
  int i = blockIdx.x * 256 + threadIdx.x;
  if (i < n) d[i] = (double)s[i];
}

// fused pack: Msh (448x320 f16, k-major dwords), OmWh (320x128 f16 k-major),
// Tp1g (64x64 f16 pairs: (T[l][j], T[l+64][j]) j=0..63, zero-filled invalid),
// Tp2g (64x32 f16 pairs: (T[l+64][64+2i], T[l+64][65+2i]), zero-filled invalid)
__global__ void k_pack(const double* __restrict__ H, const float* __restrict__ D12,
                       const double* __restrict__ sc, const double* __restrict__ Axwu,
                       const double* __restrict__ G,
                       uint* __restrict__ Msh, uint* __restrict__ OmWh,
                       uint* __restrict__ Tp1g, uint* __restrict__ Tp2g) {
  int idx = blockIdx.x * 256 + threadIdx.x;
  if (idx < 448 * 160) {
    int rr = idx / 160, d = idx % 160;
    float v[2];
#pragma unroll
    for (int e = 0; e < 2; ++e) {
      int k = 2 * d + e;
      double x;
      if (rr < 128) {
        double s = sc[rr];
        x = (k < 256) ? (-H[(256 + rr) * NTWO + k] * s)
                      : ((double)D12[rr * DINN + (k - 256)] * s);
      } else {
        int r2 = rr - 128;
        const double* src = (r2 < 256) ? (Axwu + (size_t)r2 * 448) : (G + (size_t)(r2 - 256) * 448);
        x = (k < 256) ? src[k] : src[384 + (k - 256)];
      }
      v[e] = (float)x;
    }
    Msh[((size_t)(d >> 2) * 448 + rr) * 4 + (d & 3)] = pack_f16(v[0], v[1]);
    return;
  }
  idx -= 448 * 160;
  if (idx < 320 * 64) {
    int rr = idx / 64, d = idx % 64;
    float v[2];
#pragma unroll
    for (int e = 0; e < 2; ++e) {
      int j = 2 * d + e;
      double x = (rr < 256) ? Axwu[(size_t)rr * 448 + 256 + j]
                            : G[(size_t)(rr - 256) * 448 + 256 + j];
      v[e] = (float)x;
    }
    OmWh[((size_t)(d >> 2) * 320 + rr) * 4 + (d & 3)] = pack_f16(v[0], v[1]);
    return;
  }
  idx -= 320 * 64;
  if (idx < 4096) {
    int l = idx >> 6, d = idx & 63;
    float lo = (l > d) ? (float)(-H[(256 + l) * NTWO + 256 + d] * sc[l]) : 0.0f;
    float hi = (float)(-H[(256 + l + 64) * NTWO + 256 + d] * sc[l + 64]);
    Tp1g[idx] = pack_f16(lo, hi);
    return;
  }
  idx -= 4096;
  if (idx < 2048) {
    int l = idx >> 5, i = idx & 31;
    int j0 = 64 + 2 * i, j1 = j0 + 1;
    float v0 = (l + 64 > j0) ? (float)(-H[(256 + l + 64) * NTWO + 256 + j0] * sc[l + 64]) : 0.0f;
    float v1 = (l + 64 > j1) ? (float)(-H[(256 + l + 64) * NTWO + 256 + j1] * sc[l + 64]) : 0.0f;
    Tp2g[idx] = pack_f16(v0, v1);
  }
}

// ---------------- main scan: 256 WGs x 512 threads, NS=2, 1 WG/CU ----------------
// Base matrix LDS-resident. Chain waves (0-1, one sample each): base dots from
// LDS, then BULK-load their 96 T-dwords (f16 pairs) into registers via 24
// ds_read_b128 -> chain loop is pure-register critical path (readlane, exp2,
// rcp, fma). setprio(1) around chain. Stream threads (128-447) re-stream Msh
// rows + OmW rows from L2 each step (pipelined). 2 barriers/step.
__global__ __launch_bounds__(512)
void k_scan(const float* __restrict__ u_in, const uint* __restrict__ Msh,
            const uint* __restrict__ OmWh, const uint* __restrict__ Tp1g,
            const uint* __restrict__ Tp2g, float* __restrict__ out) {
  __shared__ uint4 baseL4[40 * 128];              // 80 KB base rows k-major
  __shared__ uint Tp1L[64 * 68];                  // 17 KB, row l at l*68
  __shared__ uint Tp2L[64 * 36];                  // 9 KB, row l at l*36
  __shared__ uint __align__(16) zL[2 * 164];      // z = [x(128dw);u(32dw)] x 2
  __shared__ uint __align__(16) wvhL[2 * 64];     // w f16-packed
  const int tid = threadIdx.x;
  const int s0 = blockIdx.x * 2;
  const uint4* __restrict__ mp4 = (const uint4*)Msh;
  const uint4* __restrict__ op4 = (const uint4*)OmWh;

  // one-time init
  for (int i = tid; i < 5120; i += 512) {
    const int blk = i >> 7, r = i & 127;
    baseL4[i] = mp4[(size_t)blk * 448 + r];
  }
  for (int i = tid; i < 4096; i += 512) Tp1L[(i >> 6) * 68 + (i & 63)] = Tp1g[i];
  for (int i = tid; i < 2048; i += 512) Tp2L[(i >> 5) * 36 + (i & 31)] = Tp2g[i];
  if (tid < 256) zL[(tid >> 7) * 164 + (tid & 127)] = 0u;
  if (tid < 128) out[((size_t)(s0 + (tid >> 6)) * HORN) * DOUTN + (tid & 63)] = 0.0f;
  if (tid >= 448) {
    const int i = tid - 448, s = i >> 5, k = i & 31;
    const float* up = u_in + ((size_t)(s0 + s) * HORN) * DINN + 2 * k;
    zL[s * 164 + 128 + k] = pack_f16(up[0], up[1]);
  }
  __syncthreads();

  for (int t = 0; t < HORN - 1; ++t) {
    float a0 = 0.f, a1 = 0.f;
    float unx = 0.f, uny = 0.f;
    uint4 om[16];
    if (tid < 128) {
      // ---- chain waves: T bulk-prefetch + base dots (LDS) + pure-register chain
      const int b = tid >> 6, l = tid & 63;
      uint4 q[16], r2[8];
      {
        const uint* tp1 = Tp1L + l * 68;
        const uint* tp2 = Tp2L + l * 36;
#pragma unroll
        for (int i = 0; i < 16; ++i) q[i] = *(const uint4*)(tp1 + 4 * i);
#pragma unroll
        for (int i = 0; i < 8; ++i) r2[i] = *(const uint4*)(tp2 + 4 * i);
      }
      const uint4* zz = (const uint4*)(zL + b * 164);
      float c0 = 0.f, c1 = 0.f;
#pragma unroll 8
      for (int i = 0; i < 40; ++i) {
        const uint4 mA = baseL4[i * 128 + l];
        const uint4 mB = baseL4[i * 128 + 64 + l];
        const uint4 p = zz[i];
        c0 = fdot2(mA.x, p.x, c0); c0 = fdot2(mA.y, p.y, c0);
        c0 = fdot2(mA.z, p.z, c0); c0 = fdot2(mA.w, p.w, c0);
        c1 = fdot2(mB.x, p.x, c1); c1 = fdot2(mB.y, p.y, c1);
        c1 = fdot2(mB.z, p.z, c1); c1 = fdot2(mB.w, p.w, c1);
      }
      __builtin_amdgcn_s_setprio(1);
      float wx = 0.f, wy = 0.f;
#pragma unroll
      for (int j = 0; j < 64; ++j) {
        const float av = bcast_lane(c0, j);
        const float sx = fast_exp2(av);
        const float rc = __builtin_amdgcn_rcpf(sx + 1.0f);
        const float w = __builtin_fmaf(-2.0f, rc, 1.0f);
        if (l == (j >> 1)) { if (j & 1) wy = w; else wx = w; }
        const half2_t h = __builtin_bit_cast(half2_t, comp4(q[j >> 2], j & 3));
        c0 = __builtin_fmaf((float)h[0], w, c0);
        c1 = __builtin_fmaf((float)h[1], w, c1);
      }
#pragma unroll
      for (int j = 64; j < 128; ++j) {
        const float av = bcast_lane(c1, j - 64);
        const float sx = fast_exp2(av);
        const float rc = __builtin_amdgcn_rcpf(sx + 1.0f);
        const float w = __builtin_fmaf(-2.0f, rc, 1.0f);
        if (l == (j >> 1)) { if (j & 1) wy = w; else wx = w; }
        const int i2 = j - 64;
        const half2_t h = __builtin_bit_cast(half2_t, comp4(r2[i2 >> 3], (i2 >> 1) & 3));
        const float tv = (i2 & 1) ? (float)h[1] : (float)h[0];
        c1 = __builtin_fmaf(tv, w, c1);
      }
      __builtin_amdgcn_s_setprio(0);
      wvhL[b * 64 + l] = pack_f16(wx, wy);
    } else if (tid < 448) {
      // ---- stream threads: row = tid (128..447), both samples, 2 batches from L2
      const int row = tid;
      const uint4* z0 = (const uint4*)zL;
      const uint4* z1 = (const uint4*)(zL + 164);
      uint4 mbuf[20];
#pragma unroll
      for (int i = 0; i < 20; ++i) mbuf[i] = mp4[(size_t)i * 448 + row];
#pragma unroll
      for (int i = 0; i < 20; ++i) {
        const uint4 m = mbuf[i];
        const uint4 p = z0[i], q = z1[i];
        a0 = fdot2(m.x, p.x, a0); a0 = fdot2(m.y, p.y, a0);
        a0 = fdot2(m.z, p.z, a0); a0 = fdot2(m.w, p.w, a0);
        a1 = fdot2(m.x, q.x, a1); a1 = fdot2(m.y, q.y, a1);
        a1 = fdot2(m.z, q.z, a1); a1 = fdot2(m.w, q.w, a1);
      }
#pragma unroll
      for (int i = 0; i < 20; ++i) mbuf[i] = mp4[(size_t)(20 + i) * 448 + row];
#pragma unroll
      for (int i = 0; i < 20; ++i) {
        const uint4 m = mbuf[i];
        const uint4 p = z0[20 + i], q = z1[20 + i];
        a0 = fdot2(m.x, p.x, a0); a0 = fdot2(m.y, p.y, a0);
        a0 = fdot2(m.z, p.z, a0); a0 = fdot2(m.w, p.w, a0);
        a1 = fdot2(m.x, q.x, a1); a1 = fdot2(m.y, q.y, a1);
        a1 = fdot2(m.z, q.z, a1); a1 = fdot2(m.w, q.w, a1);
      }
      // pre-issue OmW row (consumed after B1)
      const int rr = row - 128;
#pragma unroll
      for (int i = 0; i < 16; ++i) om[i] = op4[(size_t)i * 320 + rr];
    } else {
      // ---- wave 7: u prefetch
      const int i = tid - 448, s = i >> 5, k = i & 31;
      const float* up = u_in + ((size_t)(s0 + s) * HORN + (t + 1)) * DINN + 2 * k;
      unx = up[0]; uny = up[1];
    }
    __syncthreads();  // B1: wvh ready; stream dots done; OmW in flight

    if (tid >= 128 && tid < 448) {
      const int row = tid;
      const uint4* wp0 = (const uint4*)wvhL;
      const uint4* wp1 = (const uint4*)(wvhL + 64);
#pragma unroll
      for (int i = 0; i < 16; ++i) {
        const uint4 m = om[i];
        const uint4 p = wp0[i], q = wp1[i];
        a0 = fdot2(m.x, p.x, a0); a0 = fdot2(m.y, p.y, a0);
        a0 = fdot2(m.z, p.z, a0); a0 = fdot2(m.w, p.w, a0);
        a1 = fdot2(m.x, q.x, a1); a1 = fdot2(m.y, q.y, a1);
        a1 = fdot2(m.z, q.z, a1); a1 = fdot2(m.w, q.w, a1);
      }
      if (row < 384) {
        // x rows: pack pairs into z (even lane takes odd neighbor)
        const float n0 = __shfl_down(a0, 1, 64);
        const float n1 = __shfl_down(a1, 1, 64);
        if ((row & 1) == 0) {
          const int d = (row - 128) >> 1;
          zL[d] = pack_f16(a0, n0);
          zL[164 + d] = pack_f16(a1, n1);
        }
      } else {
        const int yr = row - 384;
        out[((size_t)s0 * HORN + (t + 1)) * DOUTN + yr] = a0;
        out[((size_t)(s0 + 1) * HORN + (t + 1)) * DOUTN + yr] = a1;
      }
    } else if (tid >= 448) {
      const int i = tid - 448, s = i >> 5, k = i & 31;
      zL[s * 164 + 128 + k] = pack_f16(unx, uny);
    }
    __syncthreads();  // B2: z ready for next step
  }
}

// ---------------- host ----------------
extern "C" void kernel_launch(void* const* d_in, const int* in_sizes, int n_in,
                              void* d_out, int out_size, void* d_ws, size_t ws_size,
                              hipStream_t stream) {
  (void)in_sizes; (void)n_in; (void)out_size; (void)ws_size;
  const float* u_in = (const float*)d_in[0];
  const float* X    = (const float*)d_in[1];
  const float* Y    = (const float*)d_in[2];
  const float* B2   = (const float*)d_in[3];
  const float* C2   = (const float*)d_in[4];
  const float* D21  = (const float*)d_in[5];
  const float* D12  = (const float*)d_in[6];
  float* out = (float*)d_out;

  double* H    = (double*)d_ws;            // 640*640
  double* E    = H + 640 * 640;            // 256*256
  double* Ai   = E + 256 * 256;            // 128*128
  double* CMm  = Ai + 128 * 128;
  double* MBm  = CMm + 128 * 128;
  double* Sm   = MBm + 128 * 128;
  double* Tm   = Sm + 128 * 128;
  double* Einv = Tm + 128 * 128;           // 256*256
  double* Axwu = Einv + 256 * 256;         // 256*448
  double* G    = Axwu + 256 * 448;         // 64*448
  double* B2d  = G + 64 * 448;             // 256*64
  double* C2d  = B2d + 256 * 64;           // 64*256
  double* Dxt  = C2d + 64 * 256;           // 64*448
  double* Eye2 = Dxt + 64 * 448;           // 128*128
  double* M0d  = Eye2 + 128 * 128;
  double* Rb   = M0d + 128 * 128;
  double* scv  = Rb + 128 * 128;           // 128
  float*  F32  = (float*)(scv + 128);      // 128*128
  uint*   Msh  = (uint*)(F32 + 128 * 128); // 71680
  uint*   OmWh = Msh + 71680;              // 20480
  uint*   Tp1g = OmWh + 20480;             // 4096
  uint*   Tp2g = Tp1g + 4096;              // 2048

  dim3 blk16(16, 16);
  k_xtx<<<dim3(40, 40), blk16, 0, stream>>>(X, H);
  k_prep<<<561, 256, 0, stream>>>(H, Y, B2, C2, D21, E, scv, B2d, C2d, Dxt, Eye2);

  auto inv128 = [&](const double* A, int lda, double* Out) {
    k_ginv32<<<1, 256, 0, stream>>>(A, lda, F32);
    k_cast_f2d<<<64, 256, 0, stream>>>(F32, M0d, 128 * 128);
    // one Newton-Schulz refinement: M <- M0(2I - A M0)
    k_dgemm<<<dim3(8, 8), blk16, 0, stream>>>(128, 128, 128, A, lda, M0d, 128, -1.0, Eye2, 128, 1.0, Rb, 128);
    k_dgemm<<<dim3(8, 8), blk16, 0, stream>>>(128, 128, 128, M0d, 128, Rb, 128, 1.0, (const double*)nullptr, 0, 0.0, Out, 128);
  };

  const double* EA = E;
  const double* EB = E + 128;
  const double* EC = E + 128 * 256;
  const double* ED = E + 128 * 256 + 128;

  inv128(EA, 256, Ai);
  k_dgemm<<<dim3(8, 8), blk16, 0, stream>>>(128, 128, 128, EC, 256, Ai, 128, 1.0, (const double*)nullptr, 0, 0.0, CMm, 128);
  k_dgemm<<<dim3(8, 8), blk16, 0, stream>>>(128, 128, 128, Ai, 128, EB, 256, 1.0, (const double*)nullptr, 0, 0.0, MBm, 128);
  k_dgemm<<<dim3(8, 8), blk16, 0, stream>>>(128, 128, 128, CMm, 128, EB, 256, -1.0, ED, 256, 1.0, Sm, 128);
  inv128(Sm, 128, Tm);
  k_dgemm<<<dim3(8, 8), blk16, 0, stream>>>(128, 128, 128, Tm, 128, CMm, 128, -1.0, (const double*)nullptr, 0, 0.0, Einv + 128 * 256, 256);
  k_dgemm<<<dim3(8, 8), blk16, 0, stream>>>(128, 128, 128, MBm, 128, Tm, 128, -1.0, (const double*)nullptr, 0, 0.0, Einv + 128, 256);
  k_dgemm<<<dim3(8, 8), blk16, 0, stream>>>(128, 128, 128, MBm, 128, Einv + 128 * 256, 256, -1.0, Ai, 128, 1.0, Einv, 256);
  k_copyblk<<<64, 256, 0, stream>>>(Tm, 128, Einv + 128 * 256 + 128, 256, 128 * 128, 128);

  // Axwu = Einv @ [Fm | B1 | B2]
  k_dgemm<<<dim3(24, 16), blk16, 0, stream>>>(256, 384, 256, Einv, 256, H + 384 * NTWO, NTWO, 1.0, (const double*)nullptr, 0, 0.0, Axwu, 448);
  k_dgemm<<<dim3(4, 16), blk16, 0, stream>>>(256, 64, 256, Einv, 256, B2d, 64, 1.0, (const double*)nullptr, 0, 0.0, Axwu + 384, 448);
  // G = C2 @ Axwu + [0 | D21 | 0]
  k_dgemm<<<dim3(28, 4), blk16, 0, stream>>>(64, 448, 256, C2d, 256, Axwu, 448, 1.0, Dxt, 448, 1.0, G, 448);

  k_pack<<<384, 256, 0, stream>>>(H, D12, scv, Axwu, G, Msh, OmWh, Tp1g, Tp2g);

  k_scan<<<BATCHN / 2, 512, 0, stream>>>(u_in, Msh, OmWh, Tp1g, Tp2g, out);
}